// Round 5
// baseline (573.393 us; speedup 1.0000x reference)
//
#include <hip/hip_runtime.h>
#include <hip/hip_bf16.h>
#include <cstdint>

#define DI __device__ __forceinline__

typedef __attribute__((ext_vector_type(8))) short v8s;   // 8 bf16 (4 VGPRs)
typedef __attribute__((ext_vector_type(4))) float v4f;   // 4 f32 acc

// ---- problem constants ----
constexpr int Bc = 2, Nc = 2048, Cc = 1024, Hc = 16, Dc = 64;

DI float bfbits(uint32_t u) { union { uint32_t i; float f; } c; c.i = u; return c.f; }
DI unsigned short f2bf(float f) {
    union { float f; uint32_t u; } c; c.f = f;
    uint32_t r = c.u + 0x7FFFu + ((c.u >> 16) & 1u);   // RNE
    return (unsigned short)(r >> 16);
}
DI void unpackb8(uint4 u, float* f) {
    f[0] = bfbits(u.x << 16); f[1] = bfbits(u.x & 0xFFFF0000u);
    f[2] = bfbits(u.y << 16); f[3] = bfbits(u.y & 0xFFFF0000u);
    f[4] = bfbits(u.z << 16); f[5] = bfbits(u.z & 0xFFFF0000u);
    f[6] = bfbits(u.w << 16); f[7] = bfbits(u.w & 0xFFFF0000u);
}
DI float gpow(float g, float p) {
    if (p <= 0.f) return 1.f;
    if (g <= 0.f) return 0.f;
    return exp2f(p * log2f(g));
}

// async global->LDS, 16B per lane. LDS dest is wave-uniform base + lane*16.
typedef __attribute__((address_space(3))) uint32_t as3_u32;
typedef __attribute__((address_space(1))) uint32_t as1_u32;
DI void gload16(const void* g, void* l) {
    __builtin_amdgcn_global_load_lds((const as1_u32*)g, (as3_u32*)l, 16, 0, 0);
}

// ---------------------------------------------------------------------------
// cvt: f32 -> bf16, 8 elems/thread
// ---------------------------------------------------------------------------
__global__ __launch_bounds__(256) void cvt_bf16(
    const float* __restrict__ in, unsigned short* __restrict__ out, int n8)
{
    int i = blockIdx.x * 256 + threadIdx.x;
    if (i >= n8) return;
    float4 a = ((const float4*)in)[i * 2];
    float4 b = ((const float4*)in)[i * 2 + 1];
    ushort4 r0; r0.x = f2bf(a.x); r0.y = f2bf(a.y); r0.z = f2bf(a.z); r0.w = f2bf(a.w);
    ushort4 r1; r1.x = f2bf(b.x); r1.y = f2bf(b.y); r1.z = f2bf(b.z); r1.w = f2bf(b.w);
    ((ushort4*)out)[i * 2] = r0; ((ushort4*)out)[i * 2 + 1] = r1;
}

// ---------------------------------------------------------------------------
// transpose + cvt: in f32 [R][C] -> out bf16 [C][R].  grid (C/64, R/64)
// ---------------------------------------------------------------------------
__global__ __launch_bounds__(256) void transpose_cvt(
    const float* __restrict__ in, unsigned short* __restrict__ out, int R, int C)
{
    __shared__ float T[64][65];
    const int tid = threadIdx.x;
    const int r0 = blockIdx.y * 64, c0 = blockIdx.x * 64;
    #pragma unroll
    for (int rep = 0; rep < 4; rep++) {
        int row = (tid >> 4) + rep * 16, col = (tid & 15) * 4;
        float4 v = *reinterpret_cast<const float4*>(in + (size_t)(r0 + row) * C + c0 + col);
        T[row][col] = v.x; T[row][col + 1] = v.y; T[row][col + 2] = v.z; T[row][col + 3] = v.w;
    }
    __syncthreads();
    #pragma unroll
    for (int rep = 0; rep < 4; rep++) {
        int ocr = (tid >> 4) + rep * 16, j4 = (tid & 15) * 4;
        ushort4 w;
        w.x = f2bf(T[j4][ocr]);     w.y = f2bf(T[j4 + 1][ocr]);
        w.z = f2bf(T[j4 + 2][ocr]); w.w = f2bf(T[j4 + 3][ocr]);
        *reinterpret_cast<ushort4*>(out + (size_t)(c0 + ocr) * R + r0 + j4) = w;
    }
}

// ---------------------------------------------------------------------------
// transpose_v: vb bf16 [BH][N][D] -> vtb bf16 [BH][D][N].  grid (N/64, B*H)
// ---------------------------------------------------------------------------
__global__ __launch_bounds__(256) void transpose_v(
    const unsigned short* __restrict__ in, unsigned short* __restrict__ out)
{
    __shared__ unsigned short T[64][72];
    const int tid = threadIdx.x;
    const int n0 = blockIdx.x * 64;
    const int bh = blockIdx.y;
    const unsigned short* src = in + ((size_t)bh * Nc + n0) * Dc;
    #pragma unroll
    for (int rep = 0; rep < 2; rep++) {
        int r = (tid >> 3) + rep * 32, c = (tid & 7) * 8;
        *(uint4*)&T[r][c] = *(const uint4*)(src + (size_t)r * Dc + c);
    }
    __syncthreads();
    unsigned short* dst = out + (size_t)bh * Dc * Nc + n0;
    #pragma unroll
    for (int rep = 0; rep < 2; rep++) {
        int d = (tid >> 3) + rep * 32, c0 = (tid & 7) * 8;
        union { uint4 u; unsigned short s[8]; } w;
        #pragma unroll
        for (int j = 0; j < 8; j++) w.s[j] = T[c0 + j][d];
        *(uint4*)(dst + (size_t)d * Nc + c0) = w.u;
    }
}

// ---------------------------------------------------------------------------
// K1: qkv GEMM, 128x128 tile, 4 waves (each 64x64). A=[4096][1024] bf16,
// Bt=[3072][1024] bf16. m97-style staging: global_load_lds width=16 into
// LINEAR [128][64] LDS (gload requires contiguous dest; conflicts accepted
// per m97's measured 874 TF). Scatters q(*0.125)/k/v bf16 [B,H,N,D].
// ---------------------------------------------------------------------------
__global__ __launch_bounds__(256) void qkv_mfma(
    const unsigned short* __restrict__ A, const unsigned short* __restrict__ Bt,
    const float* __restrict__ bias,
    unsigned short* __restrict__ q, unsigned short* __restrict__ k,
    unsigned short* __restrict__ v)
{
    __shared__ unsigned short As[128][64];
    __shared__ unsigned short Bs[128][64];
    const int tid = threadIdx.x, wave = tid >> 6, lane = tid & 63;
    const int L = lane & 15, quad = lane >> 4;
    const int wr = (wave >> 1) * 64, wc = (wave & 1) * 64;
    const int row0 = blockIdx.y * 128, col0 = blockIdx.x * 128;
    const int srow = wave * 32 + (lane >> 3);   // + i*8 per instruction
    const int scol = (lane & 7) * 8;
    v4f acc[4][4];
    #pragma unroll
    for (int i = 0; i < 4; i++)
        #pragma unroll
        for (int j = 0; j < 4; j++) { acc[i][j][0]=0.f; acc[i][j][1]=0.f; acc[i][j][2]=0.f; acc[i][j][3]=0.f; }
    for (int k0 = 0; k0 < 1024; k0 += 64) {
        __syncthreads();
        #pragma unroll
        for (int i = 0; i < 4; i++) {
            gload16(A  + (size_t)(row0 + srow + i * 8) * 1024 + k0 + scol, &As[wave * 32 + i * 8][0]);
            gload16(Bt + (size_t)(col0 + srow + i * 8) * 1024 + k0 + scol, &Bs[wave * 32 + i * 8][0]);
        }
        __syncthreads();   // drains vmcnt before barrier (compiler-inserted)
        #pragma unroll
        for (int half = 0; half < 2; half++) {
            v8s af[4], bf[4];
            #pragma unroll
            for (int s = 0; s < 4; s++) {
                af[s] = *(v8s*)&As[wr + s * 16 + L][half * 32 + quad * 8];
                bf[s] = *(v8s*)&Bs[wc + s * 16 + L][half * 32 + quad * 8];
            }
            #pragma unroll
            for (int i = 0; i < 4; i++)
                #pragma unroll
                for (int j = 0; j < 4; j++)
                    acc[i][j] = __builtin_amdgcn_mfma_f32_16x16x32_bf16(af[i], bf[j], acc[i][j], 0, 0, 0);
        }
    }
    const int which = col0 >> 10;   // block-constant (128 | 1024)
    #pragma unroll
    for (int j = 0; j < 4; j++) {
        int c = col0 + wc + j * 16 + L;
        int h = (c & 1023) >> 6, d = c & 63;
        float bv = bias[c];
        #pragma unroll
        for (int i = 0; i < 4; i++) {
            #pragma unroll
            for (int reg = 0; reg < 4; reg++) {
                int rr = row0 + wr + i * 16 + quad * 4 + reg;
                int b = rr >> 11, n = rr & 2047;
                float val = acc[i][j][reg] + bv;
                size_t base = (((size_t)(b * Hc + h)) * Nc + n) * Dc + d;
                if (which == 0)      q[base] = f2bf(val * 0.125f);
                else if (which == 1) k[base] = f2bf(val);
                else                 v[base] = f2bf(val);
            }
        }
    }
}

// ---------------------------------------------------------------------------
// K2: retention via MFMA. Each block: 128 n-rows, ONE batch, one m-chunk.
// grid (N/128, H, 4): blockIdx.z = batch*2 + chunk.  (unchanged from r4)
// ---------------------------------------------------------------------------
__global__ __launch_bounds__(256, 4) void retention_mfma(
    const unsigned short* __restrict__ qb, const unsigned short* __restrict__ kb,
    const unsigned short* __restrict__ vtb,
    const float* __restrict__ mask, const float* __restrict__ gamma,
    const float* __restrict__ sprev,
    unsigned short* __restrict__ retb, float* __restrict__ pf0, float* __restrict__ pf1)
{
    __shared__ unsigned short Kt[64][72];   // K tile row-major (also spT / Q-half at init)
    __shared__ unsigned short Vt[64][72];   // V^T tile (also Q-half at init)
    __shared__ unsigned short Sm[64][72];   // masked scores (per-wave 16-row bands)
    const int tid = threadIdx.x, wave = tid >> 6, lane = tid & 63;
    const int L = lane & 15, quad = lane >> 4;
    const int h = blockIdx.y;
    const int n0 = blockIdx.x * 128;
    const int batch = blockIdx.z >> 1;
    const int chunk = blockIdx.z & 1;
    const int m_base = chunk * 1024;
    const float g = gamma[h];
    const int bh = batch * Hc + h;

    {   // init: stage Q rows [n0,n0+64) into Kt, [n0+64,n0+128) into Vt
        #pragma unroll
        for (int rep = 0; rep < 2; rep++) {
            int r = (tid >> 3) + rep * 32, ch = (tid & 7) * 8;
            *(uint4*)&Kt[r][ch] = *(const uint4*)(qb + ((size_t)bh * Nc + n0 + r) * Dc + ch);
            *(uint4*)&Vt[r][ch] = *(const uint4*)(qb + ((size_t)bh * Nc + n0 + 64 + r) * Dc + ch);
        }
    }
    __syncthreads();
    v8s qf[2][2];   // [band][k-half]
    qf[0][0] = *(v8s*)&Kt[wave * 16 + L][quad * 8];
    qf[0][1] = *(v8s*)&Kt[wave * 16 + L][32 + quad * 8];
    qf[1][0] = *(v8s*)&Vt[wave * 16 + L][quad * 8];
    qf[1][1] = *(v8s*)&Vt[wave * 16 + L][32 + quad * 8];

    v4f oacc[2][4];
    #pragma unroll
    for (int band = 0; band < 2; band++)
        #pragma unroll
        for (int s = 0; s < 4; s++) { oacc[band][s][0]=0.f; oacc[band][s][1]=0.f; oacc[band][s][2]=0.f; oacc[band][s][3]=0.f; }

    if (chunk == 0) {   // cross term: Q @ state_prev^T-layout, scaled by gamma^(n+1)
        __syncthreads();   // qf reads done before Kt overwrite
        {
            int dd = tid >> 2, e0 = (tid & 3) * 16;
            const float* sp = sprev + ((size_t)bh * 64 + dd) * 64 + e0;
            #pragma unroll
            for (int j = 0; j < 16; j++) Kt[e0 + j][dd] = f2bf(sp[j]);
        }
        __syncthreads();
        #pragma unroll
        for (int band = 0; band < 2; band++) {
            #pragma unroll
            for (int s = 0; s < 4; s++) {
                v4f a = oacc[band][s];
                a = __builtin_amdgcn_mfma_f32_16x16x32_bf16(qf[band][0], *(v8s*)&Kt[s * 16 + L][quad * 8], a, 0, 0, 0);
                a = __builtin_amdgcn_mfma_f32_16x16x32_bf16(qf[band][1], *(v8s*)&Kt[s * 16 + L][32 + quad * 8], a, 0, 0, 0);
                oacc[band][s] = a;
            }
            float cf = gpow(g, (float)(n0 + band * 64 + wave * 16 + quad * 4 + 1));
            #pragma unroll
            for (int reg = 0; reg < 4; reg++) {
                #pragma unroll
                for (int s = 0; s < 4; s++) oacc[band][s][reg] *= cf;
                cf *= g;
            }
        }
    }

    const unsigned short* kp = kb + (size_t)bh * Nc * Dc;
    const unsigned short* vt = vtb + (size_t)bh * Dc * Nc;
    const float* mbase = mask + (size_t)h * Nc * Nc;

    for (int it = 0; it < 16; ++it) {
        const int m0 = m_base + it * 64;
        __syncthreads();
        {   // K tile row-major; V^T tile row-copied from pre-transposed vtb
            #pragma unroll
            for (int rep = 0; rep < 2; rep++) {
                int r = (tid >> 3) + rep * 32, ch = (tid & 7) * 8;
                *(uint4*)&Kt[r][ch] = *(const uint4*)(kp + (size_t)(m0 + r) * Dc + ch);
                *(uint4*)&Vt[r][ch] = *(const uint4*)(vt + (size_t)r * Nc + m0 + ch);
            }
        }
        __syncthreads();
        #pragma unroll
        for (int band = 0; band < 2; band++) {
            float mv[4][4];
            #pragma unroll
            for (int s = 0; s < 4; s++)
                #pragma unroll
                for (int reg = 0; reg < 4; reg++)
                    mv[s][reg] = mbase[(size_t)(n0 + band * 64 + wave * 16 + quad * 4 + reg) * Nc + m0 + s * 16 + L];
            v4f sa[4];
            #pragma unroll
            for (int s = 0; s < 4; s++) {
                v4f a; a[0] = 0.f; a[1] = 0.f; a[2] = 0.f; a[3] = 0.f;
                a = __builtin_amdgcn_mfma_f32_16x16x32_bf16(qf[band][0], *(v8s*)&Kt[s * 16 + L][quad * 8], a, 0, 0, 0);
                a = __builtin_amdgcn_mfma_f32_16x16x32_bf16(qf[band][1], *(v8s*)&Kt[s * 16 + L][32 + quad * 8], a, 0, 0, 0);
                sa[s] = a;
            }
            #pragma unroll
            for (int s = 0; s < 4; s++)
                #pragma unroll
                for (int reg = 0; reg < 4; reg++)
                    Sm[wave * 16 + quad * 4 + reg][s * 16 + L] = f2bf(sa[s][reg] * mv[s][reg]);
            v8s af0 = *(v8s*)&Sm[wave * 16 + L][quad * 8];
            v8s af1 = *(v8s*)&Sm[wave * 16 + L][32 + quad * 8];
            #pragma unroll
            for (int s = 0; s < 4; s++) {
                oacc[band][s] = __builtin_amdgcn_mfma_f32_16x16x32_bf16(af0, *(v8s*)&Vt[s * 16 + L][quad * 8], oacc[band][s], 0, 0, 0);
                oacc[band][s] = __builtin_amdgcn_mfma_f32_16x16x32_bf16(af1, *(v8s*)&Vt[s * 16 + L][32 + quad * 8], oacc[band][s], 0, 0, 0);
            }
        }
    }

    if (chunk == 0) {
        #pragma unroll
        for (int band = 0; band < 2; band++)
            #pragma unroll
            for (int s = 0; s < 4; s++)
                #pragma unroll
                for (int reg = 0; reg < 4; reg++) {
                    int n = n0 + band * 64 + wave * 16 + quad * 4 + reg;
                    retb[((size_t)batch * Nc + n) * Cc + h * 64 + s * 16 + L] = f2bf(oacc[band][s][reg]);
                }
    } else {
        float* pd = batch ? pf1 : pf0;
        #pragma unroll
        for (int band = 0; band < 2; band++)
            #pragma unroll
            for (int s = 0; s < 4; s++)
                #pragma unroll
                for (int reg = 0; reg < 4; reg++) {
                    int n = n0 + band * 64 + wave * 16 + quad * 4 + reg;
                    pd[(size_t)n * Cc + h * 64 + s * 16 + L] = oacc[band][s][reg];
                }
    }
}

// ---------------------------------------------------------------------------
// K3a: partial state over n-chunk of 256: sum_n g^(2047-n) k_n^T v_n  (bf16 in)
// ---------------------------------------------------------------------------
__global__ __launch_bounds__(256) void state_partial(
    const unsigned short* __restrict__ kg, const unsigned short* __restrict__ vg,
    const float* __restrict__ gamma,
    float* __restrict__ partial)   // [8][B*H*64*64]
{
    __shared__ float Ks[64][65];
    __shared__ float Vs[64][65];
    __shared__ float wdec[64];
    const int chunk = blockIdx.x;
    const int bh = blockIdx.y;
    const int h = bh & 15;
    const int tid = threadIdx.x;
    const int d = tid >> 2;
    const int e0 = (tid & 3) * 16;
    const float g = gamma[h];
    const unsigned short* kbp = kg + (size_t)bh * Nc * Dc;
    const unsigned short* vbp = vg + (size_t)bh * Nc * Dc;
    float acc[16] = {};
    const int nStart = chunk * 256;
    for (int m0 = nStart; m0 < nStart + 256; m0 += 64) {
        __syncthreads();
        {
            uint4 u0 = *(const uint4*)(kbp + (size_t)(m0 + d) * 64 + e0);
            uint4 u1 = *(const uint4*)(kbp + (size_t)(m0 + d) * 64 + e0 + 8);
            float f[8];
            unpackb8(u0, f);
            #pragma unroll
            for (int j = 0; j < 8; j++) Ks[d][e0 + j] = f[j];
            unpackb8(u1, f);
            #pragma unroll
            for (int j = 0; j < 8; j++) Ks[d][e0 + 8 + j] = f[j];
            uint4 w0 = *(const uint4*)(vbp + (size_t)(m0 + d) * 64 + e0);
            uint4 w1 = *(const uint4*)(vbp + (size_t)(m0 + d) * 64 + e0 + 8);
            unpackb8(w0, f);
            #pragma unroll
            for (int j = 0; j < 8; j++) Vs[d][e0 + j] = f[j];
            unpackb8(w1, f);
            #pragma unroll
            for (int j = 0; j < 8; j++) Vs[d][e0 + 8 + j] = f[j];
        }
        if (tid < 64) wdec[tid] = gpow(g, (float)(2047 - (m0 + tid)));
        __syncthreads();
        for (int nn = 0; nn < 64; nn++) {
            float kw = Ks[nn][d] * wdec[nn];
            #pragma unroll
            for (int j = 0; j < 16; j++) acc[j] += kw * Vs[nn][e0 + j];
        }
    }
    float* pp = partial + (size_t)chunk * (Bc * Hc * Dc * Dc)
              + ((size_t)bh * 64 + d) * 64 + e0;
    #pragma unroll
    for (int j = 0; j < 16; j++) pp[j] = acc[j];
}

// K3b: state = sum_chunks partial + state_prev * g^N
__global__ __launch_bounds__(256) void state_reduce(
    const float* __restrict__ partial,
    const float* __restrict__ sprev,
    const float* __restrict__ gamma,
    float* __restrict__ outState)
{
    const int idx = blockIdx.x * 256 + threadIdx.x;
    const int bh = idx >> 12;
    const int h = bh & 15;
    const float g = gamma[h];
    float acc = sprev[idx] * gpow(g, 2048.f);
    #pragma unroll
    for (int c = 0; c < 8; c++) acc += partial[(size_t)c * (Bc * Hc * Dc * Dc) + idx];
    outState[idx] = acc;
}

// ---------------------------------------------------------------------------
// K4: out GEMM, 128x128 tile, fused with partial add.
// A = f2bf(retb[bf16] + pf{0,1}[f32]) staged via VGPR into padded LDS;
// B = Wout^T bf16 staged via global_load_lds into linear LDS.
// ---------------------------------------------------------------------------
__global__ __launch_bounds__(256) void out_mfma(
    const unsigned short* __restrict__ Ar,   // retb [4096][1024] bf16
    const float* __restrict__ pf0, const float* __restrict__ pf1,
    const unsigned short* __restrict__ Bt,   // wot [1024][1024] bf16
    const float* __restrict__ bias,
    float* __restrict__ out)                 // [4096][1024] f32
{
    __shared__ unsigned short As[128][72];   // padded (VGPR-staged, fused add)
    __shared__ unsigned short Bs[128][64];   // linear (gload)
    const int tid = threadIdx.x, wave = tid >> 6, lane = tid & 63;
    const int L = lane & 15, quad = lane >> 4;
    const int wr = (wave >> 1) * 64, wc = (wave & 1) * 64;
    const int row0 = blockIdx.y * 128, col0 = blockIdx.x * 128;
    const int srow = wave * 32 + (lane >> 3);
    const int scol = (lane & 7) * 8;
    v4f acc[4][4];
    #pragma unroll
    for (int i = 0; i < 4; i++)
        #pragma unroll
        for (int j = 0; j < 4; j++) { acc[i][j][0]=0.f; acc[i][j][1]=0.f; acc[i][j][2]=0.f; acc[i][j][3]=0.f; }
    for (int k0 = 0; k0 < 1024; k0 += 64) {
        __syncthreads();
        #pragma unroll
        for (int i = 0; i < 4; i++)
            gload16(Bt + (size_t)(col0 + srow + i * 8) * 1024 + k0 + scol, &Bs[wave * 32 + i * 8][0]);
        #pragma unroll
        for (int rep = 0; rep < 4; rep++) {
            int r = (tid >> 3) + rep * 32, cg = (tid & 7) * 8;
            int rr = row0 + r;
            uint4 a = *(const uint4*)(Ar + (size_t)rr * 1024 + k0 + cg);
            const float* pf = (rr & 2048) ? pf1 : pf0;
            const float4* pp = (const float4*)(pf + (size_t)(rr & 2047) * 1024 + k0 + cg);
            float fa[8]; unpackb8(a, fa);
            float4 x0 = pp[0], x1 = pp[1];
            ushort4 w0, w1;
            w0.x = f2bf(fa[0] + x0.x); w0.y = f2bf(fa[1] + x0.y);
            w0.z = f2bf(fa[2] + x0.z); w0.w = f2bf(fa[3] + x0.w);
            w1.x = f2bf(fa[4] + x1.x); w1.y = f2bf(fa[5] + x1.y);
            w1.z = f2bf(fa[6] + x1.z); w1.w = f2bf(fa[7] + x1.w);
            *(ushort4*)&As[r][cg] = w0;
            *(ushort4*)&As[r][cg + 4] = w1;
        }
        __syncthreads();
        #pragma unroll
        for (int half = 0; half < 2; half++) {
            v8s af[4], bf[4];
            #pragma unroll
            for (int s = 0; s < 4; s++) {
                af[s] = *(v8s*)&As[wr + s * 16 + L][half * 32 + quad * 8];
                bf[s] = *(v8s*)&Bs[wc + s * 16 + L][half * 32 + quad * 8];
            }
            #pragma unroll
            for (int i = 0; i < 4; i++)
                #pragma unroll
                for (int j = 0; j < 4; j++)
                    acc[i][j] = __builtin_amdgcn_mfma_f32_16x16x32_bf16(af[i], bf[j], acc[i][j], 0, 0, 0);
        }
    }
    #pragma unroll
    for (int j = 0; j < 4; j++) {
        int c = col0 + wc + j * 16 + L;
        float bv = bias[c];
        #pragma unroll
        for (int i = 0; i < 4; i++) {
            #pragma unroll
            for (int reg = 0; reg < 4; reg++) {
                int rr = row0 + wr + i * 16 + quad * 4 + reg;
                out[(size_t)rr * 1024 + c] = acc[i][j][reg] + bv;
            }
        }
    }
}

extern "C" void kernel_launch(void* const* d_in, const int* in_sizes, int n_in,
                              void* d_out, int out_size, void* d_ws, size_t ws_size,
                              hipStream_t stream) {
    (void)in_sizes; (void)n_in; (void)out_size; (void)ws_size;
    const float* x     = (const float*)d_in[0]; // [B,N,C]
    const float* mask  = (const float*)d_in[1]; // [H,N,N]
    const float* gamma = (const float*)d_in[2]; // [H]
    const float* sprev = (const float*)d_in[3]; // [B,H,D,D]
    const float* Wqkv  = (const float*)d_in[4]; // [C,3C]
    const float* bqkv  = (const float*)d_in[5]; // [3C]
    const float* Wout  = (const float*)d_in[6]; // [C,C]
    const float* bout  = (const float*)d_in[7]; // [C]

    // Workspace layout (total 60 MB):
    //  [ 0.0, 8.4)  qb   bf16 [B,H,N,D]
    //  [ 8.4,16.8)  kb   bf16
    //  [16.8,25.2)  vb   bf16; ALIAS pf0 f32 [N,C] batch-0 partial (dead after state/transpose)
    //  [25.2,33.6)  retb bf16 [B,N,C]
    //  [33.6,35.7)  wot  bf16 [1024,1024]
    //  [35.7,39.8)  part f32 state partials
    //  [39.8,48.2)  xb   bf16 [4096,1024]; ALIAS vtb bf16 [B,H,D,N] (after qkv)
    //  [48.2,54.5)  wqt  bf16 [3072,1024]
    //  [54.5,62.9)  pf1  f32 [N,C] batch-1 partial
    char* W = (char*)d_ws;
    unsigned short* qb   = (unsigned short*)(W);
    unsigned short* kb   = (unsigned short*)(W + 8388608);
    unsigned short* vb   = (unsigned short*)(W + 16777216);
    float*          pf0  = (float*)        (W + 16777216);   // alias vb
    unsigned short* retb = (unsigned short*)(W + 25165824);
    unsigned short* wot  = (unsigned short*)(W + 33554432);
    float*          part = (float*)        (W + 35651584);
    unsigned short* xb   = (unsigned short*)(W + 39845888);
    unsigned short* vtb  = (unsigned short*)(W + 39845888);  // alias xb
    unsigned short* wqt  = (unsigned short*)(W + 48234496);
    float*          pf1  = (float*)        (W + 54525952);

    float* out      = (float*)d_out;                          // [B,N,C]
    float* outState = (float*)d_out + (size_t)Bc * Nc * Cc;   // [B,H,D,D]

    cvt_bf16<<<2048, 256, 0, stream>>>(x, xb, 524288);
    transpose_cvt<<<dim3(48, 16), 256, 0, stream>>>(Wqkv, wqt, 1024, 3072);
    transpose_cvt<<<dim3(16, 16), 256, 0, stream>>>(Wout, wot, 1024, 1024);
    qkv_mfma<<<dim3(24, 32), 256, 0, stream>>>(xb, wqt, bqkv, qb, kb, vb);
    transpose_v<<<dim3(32, 32), 256, 0, stream>>>(vb, vtb);       // vb -> vtb (over dead xb)
    state_partial<<<dim3(8, 32), 256, 0, stream>>>(kb, vb, gamma, part);
    state_reduce<<<512, 256, 0, stream>>>(part, sprev, gamma, outState);
    retention_mfma<<<dim3(16, 16, 4), 256, 0, stream>>>(qb, kb, vtb, mask, gamma, sprev,
                                                        retb, pf0, pf1);  // pf0 over dead vb
    out_mfma<<<dim3(8, 32), 256, 0, stream>>>(retb, pf0, pf1, wot, bout, out);
}